// Round 7
// baseline (145.049 us; speedup 1.0000x reference)
//
#include <hip/hip_runtime.h>
#include <hip/hip_fp16.h>

// BasisFunction2D, round 17: RESUBMIT of R16 (bench infra failed twice;
// kernel never ran). Theory unchanged:
// R14/R15 post-mortem: VGPR_Count=64 + WRITE_SIZE=22.6MB scratch in BOTH --
// __launch_bounds__(1024,{1,4}) does NOT move this allocator's 8-waves/EU
// target. Two-pronged fix, same failure mode, separable signals:
//  (a) __attribute__((amdgpu_waves_per_eu(4,4))): pin the backend to our
//      true LDS-limited occupancy (1 blk x 16 waves / 4 SIMD), VGPR cap 128.
//      Signal: VGPR_Count rises.
//  (b) live-across-stage z-table packed 32 -> 20 regs: 16 dwords of fp16
//      w-pairs (2 j/dword) + 4 dwords of 4-bit grid indices (8 j/dword).
//      Unpack ~4 VALU/j in compute (~0.3 us). Signal: WRITE_SIZE ~0 even
//      if VGPR stays 64.
// Everything else identical to R15 (proven stage shape, CSTRIDE 133,
// 153.7 KB LDS, grid 256, hipMemsetAsync zeroing).
// Predict: VGPR 64->~96-120, WRITE 22.6MB->~160KB, kernel 48->13-17 us,
// dur -> ~114-120, absmax exactly 0.0009765625.

#define NG        16
#define NB        17              // NG+1
#define IN_X      32
#define IN_Z      32
#define OUT_DIM   64
#define BATCH     512
#define CELLS     (NB * NB)       // 289
#define CSTRIDE   133             // 4*33 + 1: odd cell stride (bank spread)
#define ILSTRIDE  33              // per-i row stride inside a cell
#define XSTR_A    (NB * CSTRIDE)  // 2261: gx -> +17 cells
#define STASKS    (CELLS * 32)    // 9248 float4-pair staging tasks

typedef __fp16 h2v __attribute__((ext_vector_type(2)));

// pack two floats as fp16 pair (v_cvt_pkrtz, 1 instr): lo = a, hi = b
__device__ __forceinline__ unsigned pack_h2(float a, float b) {
    h2v v = __builtin_amdgcn_cvt_pkrtz(a, b);
    return __builtin_bit_cast(unsigned, v);
}
__device__ __forceinline__ __half2 u2h(unsigned u) {
    return __builtin_bit_cast(__half2, u);
}

__device__ __forceinline__ void grid_coord(float v,
                                           const float* __restrict__ borders,
                                           const float* __restrict__ inv_len,
                                           int& idx, float& w) {
    float e   = expf(-fabsf(v));
    float cdf = (v > 0.f) ? (1.f - 0.5f * e) : (0.5f * e);
    int t = (int)(cdf * 16.f);
    t = t < 0 ? 0 : (t > NG - 1 ? NG - 1 : t);
    idx = t;
    w = (v - borders[t]) * inv_len[t];
}

__global__ __launch_bounds__(1024)
__attribute__((amdgpu_waves_per_eu(4, 4)))
void bf2d_fused(const float* __restrict__ x,
                const float* __restrict__ z,
                const float* __restrict__ borders,
                const float* __restrict__ inv_len,
                const float* __restrict__ P,
                float* __restrict__ out) {
    // lds[cell*133 + il*33 + j] = half2 (P[cell,o0,i,j], P[cell,o1,i,j])
    __shared__ unsigned lds[CELLS * CSTRIDE];   // 38437 dwords = 153748 B

    const int tid = threadIdx.x;                // 1024 threads
    const int op  = blockIdx.x & 31;            // o-pair
    const int iq  = blockIdx.x >> 5;            // i-quad 0..7
    const int o0  = op * 2;
    const int b   = tid & (BATCH - 1);
    const int ih  = tid >> 9;                   // 0 or 1
    const int il0 = 2 * ih, il1 = 2 * ih + 1;

    // P float index: cell*65536 + o*1024 + i*32 + j
    const float* Pb = P + (size_t)o0 * 1024 + iq * 128;

    // ---- depth-1 prefetch of stage iter 0 (tid < 1024 < STASKS always) ----
    float4 a0v, b0v;
    {
        const int c = tid >> 5, f4 = tid & 31;
        const float* g = Pb + (size_t)c * 65536 + f4 * 4;
        a0v = *(const float4*)g;                // o0 stripe, 512-B bursts
        b0v = *(const float4*)(g + 1024);       // o1 stripe
    }

    // ---- packed per-thread z-table (20 regs live across the stage) ----
    // zw[t]   = fp16 pair (w_{2t}, w_{2t+1})
    // zidx[d] = 8 x 4-bit grid indices, nibble (j&7) of dword (j>>3)
    unsigned zw[16];
    unsigned zidx[4] = {0u, 0u, 0u, 0u};
    #pragma unroll
    for (int t = 0; t < 16; ++t) {
        int i0, i1; float w0, w1;
        grid_coord(z[(2 * t)     * BATCH + b], borders, inv_len, i0, w0);
        grid_coord(z[(2 * t + 1) * BATCH + b], borders, inv_len, i1, w1);
        zw[t] = pack_h2(w0, w1);
        zidx[t >> 2] |= ((unsigned)i0 << (((2 * t)     & 7) * 4))
                      | ((unsigned)i1 << (((2 * t + 1) & 7) * 4));
    }
    int xi0, xi1; float xw0f, xw1f;
    grid_coord(x[(iq * 4 + il0) * BATCH + b], borders, inv_len, xi0, xw0f);
    grid_coord(x[(iq * 4 + il1) * BATCH + b], borders, inv_len, xi1, xw1f);
    const __half2 wx0 = u2h(pack_h2(xw0f, xw0f));
    const __half2 wx1 = u2h(pack_h2(xw1f, xw1f));
    const int xo0 = xi0 * XSTR_A + il0 * ILSTRIDE;
    const int xo1 = xi1 * XSTR_A + il1 * ILSTRIDE;

    // ---- stage iter 0 (loads already in flight) ----
    {
        const int c = tid >> 5, f4 = tid & 31;
        unsigned* d = &lds[c * CSTRIDE + (f4 >> 3) * ILSTRIDE
                           + ((f4 & 7) << 2)];
        d[0] = pack_h2(a0v.x, b0v.x);
        d[1] = pack_h2(a0v.y, b0v.y);
        d[2] = pack_h2(a0v.z, b0v.z);
        d[3] = pack_h2(a0v.w, b0v.w);
    }
    // ---- stage iters 1..9, proven R10 shape (compiler pipelines) ----
    #pragma unroll
    for (int it = 1; it < 10; ++it) {
        const int k = tid + it * 1024;
        if (k < STASKS) {
            const int c  = k >> 5;
            const int f4 = k & 31;              // il = f4>>3, j4 = (f4&7)*4
            const float* g = Pb + (size_t)c * 65536 + f4 * 4;
            const float4 a = *(const float4*)g;           // o0 stripe
            const float4 bb = *(const float4*)(g + 1024); // o1 stripe
            unsigned* d = &lds[c * CSTRIDE + (f4 >> 3) * ILSTRIDE
                               + ((f4 & 7) << 2)];
            d[0] = pack_h2(a.x, bb.x);
            d[1] = pack_h2(a.y, bb.y);
            d[2] = pack_h2(a.z, bb.z);
            d[3] = pack_h2(a.w, bb.w);
        }
    }
    __syncthreads();

    // ---- compute: j fully unrolled, tables unpacked from 20 VGPRs ----
    __half2 acc0 = __float2half2_rn(0.f);       // il0 accumulator (o0,o1)
    __half2 acc1 = __float2half2_rn(0.f);       // il1 accumulator
    #pragma unroll
    for (int j = 0; j < IN_Z; ++j) {
        const unsigned uw   = zw[j >> 1];
        const unsigned wz_u = (j & 1) ? ((uw & 0xFFFF0000u) | (uw >> 16))
                                      : ((uw & 0x0000FFFFu) | (uw << 16));
        const __half2 wz = u2h(wz_u);
        const int idx = (int)((zidx[j >> 3] >> ((j & 7) * 4)) & 0xFu);
        const int zo  = idx * CSTRIDE + j;
        {
            const int base = xo0 + zo;
            const __half2 q0 = u2h(lds[base]);
            const __half2 q1 = u2h(lds[base + CSTRIDE]);          // read2
            const __half2 v0 = u2h(lds[base + XSTR_A]);
            const __half2 v1 = u2h(lds[base + XSTR_A + CSTRIDE]); // read2
            const __half2 zlo = __hfma2(wz, __hsub2(q1, q0), q0);
            const __half2 zhi = __hfma2(wz, __hsub2(v1, v0), v0);
            acc0 = __hadd2(acc0, __hfma2(wx0, __hsub2(zhi, zlo), zlo));
        }
        {
            const int base = xo1 + zo;
            const __half2 q0 = u2h(lds[base]);
            const __half2 q1 = u2h(lds[base + CSTRIDE]);
            const __half2 v0 = u2h(lds[base + XSTR_A]);
            const __half2 v1 = u2h(lds[base + XSTR_A + CSTRIDE]);
            const __half2 zlo = __hfma2(wz, __hsub2(q1, q0), q0);
            const __half2 zhi = __hfma2(wz, __hsub2(v1, v0), v0);
            acc1 = __hadd2(acc1, __hfma2(wx1, __hsub2(zhi, zlo), zlo));
        }
    }

    // f32 combine of the two per-il half2 partial sums
    const float accx = __low2float(acc0)  + __low2float(acc1);
    const float accy = __high2float(acc0) + __high2float(acc1);

    atomicAdd(&out[o0 * BATCH + b],       accx);
    atomicAdd(&out[(o0 + 1) * BATCH + b], accy);
}

extern "C" void kernel_launch(void* const* d_in, const int* in_sizes, int n_in,
                              void* d_out, int out_size, void* d_ws, size_t ws_size,
                              hipStream_t stream) {
    const float* x       = (const float*)d_in[0];   // (32, 512)
    const float* z       = (const float*)d_in[1];   // (32, 512)
    const float* P       = (const float*)d_in[2];   // (17,17,64,32,32)
    const float* borders = (const float*)d_in[3];   // (17,)
    const float* inv_len = (const float*)d_in[4];   // (16,)
    float* out = (float*)d_out;                     // (64, 512) = 32768

    hipMemsetAsync(out, 0, OUT_DIM * BATCH * sizeof(float), stream);
    bf2d_fused<<<dim3(32 * 8), dim3(1024), 0, stream>>>(
        x, z, borders, inv_len, P, out);
}

// Round 8
// 124.651 us; speedup vs baseline: 1.1636x; 1.1636x over previous
//
#include <hip/hip_runtime.h>
#include <hip/hip_fp16.h>

// BasisFunction2D, round 18: fused kernel, ZERO live state across the stage.
// R14-R17 post-mortem: any per-thread z-table (32 or 20 dwords) goes to
// scratch no matter what (VGPR_Count pinned at 64 by the allocator across
// launch_bounds(1024,{1,4}) AND amdgpu_waves_per_eu(4,4); packing the table
// smaller made WRITE_SIZE grow 22.6->41 MB). Register tables are dead.
// Fix: recompute z grid-coords INSIDE the compute loop -- per j, load
// z[j*512+b] (4 B/lane coalesced, L2-warm; half of R13's zc reload bytes)
// and run grid_coord inline with borders/inv_len staged in 132 B of spare
// LDS. ~14 VALU/j extra (~1 us on a 20%-busy VALU); live-across-stage
// state: none -> no spill. Keeps fusion's wins (no precompute dispatch, no
// xc/zc round-trip). Stage loop = plain proven R10 shape. Math op-for-op
// identical to R13's passing path.
// Predict: WRITE 41 MB -> ~2.3 MB (spill-kill confirmation), kernel 51 ->
// 16-19 us, dur 145 -> ~117-122, absmax exactly 0.0009765625.
// If WRITE collapses but dur >= 123: fusion gains nothing over two-kernel
// -> fill-dominated roofline, declare next round.

#define NG        16
#define NB        17              // NG+1
#define IN_X      32
#define IN_Z      32
#define OUT_DIM   64
#define BATCH     512
#define CELLS     (NB * NB)       // 289
#define CSTRIDE   133             // 4*33 + 1: odd cell stride (bank spread)
#define ILSTRIDE  33              // per-i row stride inside a cell
#define XSTR_A    (NB * CSTRIDE)  // 2261: gx -> +17 cells
#define STASKS    (CELLS * 32)    // 9248 float4-pair staging tasks

typedef __fp16 h2v __attribute__((ext_vector_type(2)));

// pack two floats as fp16 pair (v_cvt_pkrtz, 1 instr): lo = a, hi = b
__device__ __forceinline__ unsigned pack_h2(float a, float b) {
    h2v v = __builtin_amdgcn_cvt_pkrtz(a, b);
    return __builtin_bit_cast(unsigned, v);
}
__device__ __forceinline__ __half2 u2h(unsigned u) {
    return __builtin_bit_cast(__half2, u);
}

// grid_coord against the LDS-staged tables (tabs[0..16]=borders,
// tabs[17..32]=inv_len). Same float ops as the original -> bit-identical.
__device__ __forceinline__ void grid_coord_lds(float v,
                                               const float* __restrict__ tabs,
                                               int& idx, float& w) {
    float e   = expf(-fabsf(v));
    float cdf = (v > 0.f) ? (1.f - 0.5f * e) : (0.5f * e);
    int t = (int)(cdf * 16.f);
    t = t < 0 ? 0 : (t > NG - 1 ? NG - 1 : t);
    idx = t;
    w = (v - tabs[t]) * tabs[NB + t];
}

__global__ __launch_bounds__(1024)
void bf2d_fused(const float* __restrict__ x,
                const float* __restrict__ z,
                const float* __restrict__ borders,
                const float* __restrict__ inv_len,
                const float* __restrict__ P,
                float* __restrict__ out) {
    // lds[cell*133 + il*33 + j] = half2 (P[cell,o0,i,j], P[cell,o1,i,j])
    __shared__ unsigned lds[CELLS * CSTRIDE];   // 38437 dwords = 153748 B
    __shared__ float tabs[NB + NG];             // +132 B, total 153880 B

    const int tid = threadIdx.x;                // 1024 threads
    const int op  = blockIdx.x & 31;            // o-pair
    const int iq  = blockIdx.x >> 5;            // i-quad 0..7
    const int o0  = op * 2;
    const int b   = tid & (BATCH - 1);
    const int ih  = tid >> 9;                   // 0 or 1
    const int il0 = 2 * ih, il1 = 2 * ih + 1;

    if (tid < NB + NG)
        tabs[tid] = (tid < NB) ? borders[tid] : inv_len[tid - NB];

    // ---- stage P[:, o0:o0+2, iq*4:(iq+1)*4, :]: proven R10 shape ----
    // P float index: cell*65536 + o*1024 + i*32 + j
    const float* Pb = P + (size_t)o0 * 1024 + iq * 128;
    #pragma unroll
    for (int it = 0; it < 10; ++it) {
        const int k = tid + it * 1024;
        if (k < STASKS) {
            const int c  = k >> 5;
            const int f4 = k & 31;              // il = f4>>3, j4 = (f4&7)*4
            const float* g = Pb + (size_t)c * 65536 + f4 * 4;
            const float4 a = *(const float4*)g;           // o0 stripe
            const float4 bb = *(const float4*)(g + 1024); // o1 stripe
            unsigned* d = &lds[c * CSTRIDE + (f4 >> 3) * ILSTRIDE
                               + ((f4 & 7) << 2)];
            d[0] = pack_h2(a.x, bb.x);
            d[1] = pack_h2(a.y, bb.y);
            d[2] = pack_h2(a.z, bb.z);
            d[3] = pack_h2(a.w, bb.w);
        }
    }
    __syncthreads();

    // ---- x grid-coords (2 per thread, from LDS tables) ----
    int xi0, xi1; float xw0f, xw1f;
    grid_coord_lds(x[(iq * 4 + il0) * BATCH + b], tabs, xi0, xw0f);
    grid_coord_lds(x[(iq * 4 + il1) * BATCH + b], tabs, xi1, xw1f);
    const __half2 wx0 = u2h(pack_h2(xw0f, xw0f));
    const __half2 wx1 = u2h(pack_h2(xw1f, xw1f));
    const int xo0 = xi0 * XSTR_A + il0 * ILSTRIDE;
    const int xo1 = xi1 * XSTR_A + il1 * ILSTRIDE;

    // ---- compute: z coords recomputed per j, NO table state ----
    const float* zp = z + b;                    // z[j*512 + b], coalesced
    __half2 acc0 = __float2half2_rn(0.f);       // il0 accumulator (o0,o1)
    __half2 acc1 = __float2half2_rn(0.f);       // il1 accumulator
    #pragma unroll 4
    for (int j = 0; j < IN_Z; ++j) {
        int zi; float zwf;
        grid_coord_lds(zp[j * BATCH], tabs, zi, zwf);
        const unsigned wzu = pack_h2(zwf, zwf);
        const __half2 wz = u2h(wzu);
        const int zo = zi * CSTRIDE + j;
        {
            const int base = xo0 + zo;
            const __half2 q0 = u2h(lds[base]);
            const __half2 q1 = u2h(lds[base + CSTRIDE]);          // read2
            const __half2 v0 = u2h(lds[base + XSTR_A]);
            const __half2 v1 = u2h(lds[base + XSTR_A + CSTRIDE]); // read2
            const __half2 zlo = __hfma2(wz, __hsub2(q1, q0), q0);
            const __half2 zhi = __hfma2(wz, __hsub2(v1, v0), v0);
            acc0 = __hadd2(acc0, __hfma2(wx0, __hsub2(zhi, zlo), zlo));
        }
        {
            const int base = xo1 + zo;
            const __half2 q0 = u2h(lds[base]);
            const __half2 q1 = u2h(lds[base + CSTRIDE]);
            const __half2 v0 = u2h(lds[base + XSTR_A]);
            const __half2 v1 = u2h(lds[base + XSTR_A + CSTRIDE]);
            const __half2 zlo = __hfma2(wz, __hsub2(q1, q0), q0);
            const __half2 zhi = __hfma2(wz, __hsub2(v1, v0), v0);
            acc1 = __hadd2(acc1, __hfma2(wx1, __hsub2(zhi, zlo), zlo));
        }
    }

    // f32 combine of the two per-il half2 partial sums
    const float accx = __low2float(acc0)  + __low2float(acc1);
    const float accy = __high2float(acc0) + __high2float(acc1);

    atomicAdd(&out[o0 * BATCH + b],       accx);
    atomicAdd(&out[(o0 + 1) * BATCH + b], accy);
}

extern "C" void kernel_launch(void* const* d_in, const int* in_sizes, int n_in,
                              void* d_out, int out_size, void* d_ws, size_t ws_size,
                              hipStream_t stream) {
    const float* x       = (const float*)d_in[0];   // (32, 512)
    const float* z       = (const float*)d_in[1];   // (32, 512)
    const float* P       = (const float*)d_in[2];   // (17,17,64,32,32)
    const float* borders = (const float*)d_in[3];   // (17,)
    const float* inv_len = (const float*)d_in[4];   // (16,)
    float* out = (float*)d_out;                     // (64, 512) = 32768

    hipMemsetAsync(out, 0, OUT_DIM * BATCH * sizeof(float), stream);
    bf2d_fused<<<dim3(32 * 8), dim3(1024), 0, stream>>>(
        x, z, borders, inv_len, P, out);
}